// Round 20
// baseline (112.384 us; speedup 1.0000x reference)
//
#include <hip/hip_runtime.h>

#define N_NODES 50000
#define N_EDGES 600000
#define D 128
#define SCAN_B 256
#define NB ((N_NODES + SCAN_B - 1) / SCAN_B)   // 196
#define REP 4
#define FXSHIFT 44
#define GEMM_BLOCKS ((N_NODES + 63) / 64)       // 782
#define FILL_BLOCKS ((N_EDGES + 255) / 256)     // 2344
#define GATHER_GROUPS ((N_NODES + 3) / 4)       // 12500
#define ZERO_BLOCKS 392

typedef __attribute__((ext_vector_type(8))) short short8;
typedef __attribute__((ext_vector_type(4))) float f32x4;
typedef unsigned long long u64;

__device__ __forceinline__ ushort f2bf(float f) {
    unsigned u = __float_as_uint(f);
    unsigned r = (u + 0x7FFFu + ((u >> 16) & 1u)) >> 16;   // RNE
    return (ushort)r;
}
__device__ __forceinline__ float bf2f(ushort h) {
    return __uint_as_float(((unsigned)h) << 16);
}

// ---------------------------------------------------------------------------
// W fragment computation (bf16 hi only), MFMA B-operand lane order.
// ---------------------------------------------------------------------------
__device__ __forceinline__ void wfrag_body(int t, const float* __restrict__ W,
                                           ushort* __restrict__ wfh) {
    int lane = t & 63;
    int ks   = (t >> 6) & 3;
    int ct   = t >> 8;
    int n  = ct * 16 + (lane & 15);
    int k0 = ks * 32 + (lane >> 4) * 8;
    ushort hv[8];
#pragma unroll
    for (int j = 0; j < 8; ++j) hv[j] = f2bf(W[(k0 + j) * D + n]);
    size_t base = (((size_t)ct * 4 + ks) * 64 + lane) * 8;
#pragma unroll
    for (int j = 0; j < 8; ++j) wfh[base + j] = hv[j];
}

// ---------------------------------------------------------------------------
// Prep (fat): blocks [0,ZERO_BLOCKS) zero degp+flags; the last 8 do wfrag.
// ---------------------------------------------------------------------------
__global__ void prep_kernel(ulonglong2* __restrict__ zp, int n2,
                            const float* __restrict__ W,
                            ushort* __restrict__ wfh) {
    if (blockIdx.x < ZERO_BLOCKS) {
        int i = blockIdx.x * 256 + threadIdx.x;
        if (i < n2) zp[i] = make_ulonglong2(0ull, 0ull);
    } else {
        wfrag_body((blockIdx.x - ZERO_BLOCKS) * 256 + threadIdx.x, W, wfh);
    }
}

// ---------------------------------------------------------------------------
// Per-edge: one packed u64 atomic. degp INTERLEAVED [node*REP + r].
// ---------------------------------------------------------------------------
__global__ void deg_cnt_kernel(const int* __restrict__ dst,
                               const float* __restrict__ ew,
                               u64* __restrict__ degp) {
    int e = blockIdx.x * 256 + threadIdx.x;
    if (e < N_EDGES) {
        int d = dst[e];
        int r = blockIdx.x & (REP - 1);
        u64 fx = (u64)llrintf(ew[e] * 16777216.0f);
        atomicAdd(&degp[(size_t)d * REP + r], (1ull << FXSHIFT) | fx);
    }
}

// ---------------------------------------------------------------------------
// Single-pass fused scan, wave-parallel aggregate rake (R13-proven).
// ---------------------------------------------------------------------------
__global__ void scan_fused_kernel(const u64* __restrict__ degp,
                                  float* __restrict__ dinv,
                                  int* __restrict__ off,
                                  int* __restrict__ cursor,
                                  u64* __restrict__ flags) {
    __shared__ int s[SCAN_B];
    __shared__ int sbase_sh;
    int t = threadIdx.x;
    int i = blockIdx.x * SCAN_B + t;
    int v = 0;
    u64 pr[REP];
    if (i < N_NODES) {
        u64 fxsum = 0;
        int c = 0;
        const u64* dp = degp + (size_t)i * REP;
#pragma unroll
        for (int r = 0; r < REP; ++r) {
            pr[r] = dp[r];
            fxsum += pr[r] & ((1ull << FXSHIFT) - 1);
            c += (int)(pr[r] >> FXSHIFT);
        }
        dinv[i] = rsqrtf(1.0f + (float)fxsum * (1.0f / 16777216.0f));
        v = c;
    }
    s[t] = v;
    __syncthreads();
    for (int o = 1; o < SCAN_B; o <<= 1) {
        int x = (t >= o) ? s[t - o] : 0;
        __syncthreads();
        s[t] += x;
        __syncthreads();
    }
    int localExcl = s[t] - v;
    int blockSum  = s[SCAN_B - 1];

    if (t == 0) {
        __hip_atomic_store(&flags[blockIdx.x], (1ull << 62) | (u64)blockSum,
                           __ATOMIC_RELEASE, __HIP_MEMORY_SCOPE_AGENT);
    }
    if (t < 64) {
        u64 sum = 0;
        for (int j0 = 0; j0 < (int)blockIdx.x; j0 += 64) {
            int j = j0 + t;
            u64 f = 0;
            if (j < (int)blockIdx.x) {
                do {
                    f = __hip_atomic_load(&flags[j], __ATOMIC_ACQUIRE,
                                          __HIP_MEMORY_SCOPE_AGENT);
                } while (f == 0ull);
            }
            sum += f & ((1ull << 62) - 1);
        }
#pragma unroll
        for (int o = 32; o > 0; o >>= 1)
            sum += (u64)__shfl_xor((long long)sum, o);
        if (t == 0) sbase_sh = (int)sum;
    }
    __syncthreads();

    if (i < N_NODES) {
        int o = localExcl + sbase_sh;
        off[i] = o;
        int run = o;
        int* cp = cursor + (size_t)i * REP;
#pragma unroll
        for (int r = 0; r < REP; ++r) {
            cp[r] = run;
            run += (int)(pr[r] >> FXSHIFT);
        }
    }
    if (i == 0) off[N_NODES] = N_EDGES;
}

// ---------------------------------------------------------------------------
// Fat compute kernel (R16-proven structure): blocks [0,GEMM_BLOCKS) = gemm
// 64-row tiles (h = x_hi * W_hi, row-split waves); rest = fill.
// Fill writes PACKED u32 edges: (norm_bf16 << 16) | src_u16 (src < 65536).
// ---------------------------------------------------------------------------
__global__ __launch_bounds__(256) void fused_fg_kernel(
        const float* __restrict__ x,
        const ushort* __restrict__ wfh,
        ushort* __restrict__ hbf,
        const int* __restrict__ src, const int* __restrict__ dst,
        const float* __restrict__ ew, const float* __restrict__ dinv,
        int* __restrict__ cursor, unsigned* __restrict__ edge_s) {
    __shared__ __attribute__((aligned(16))) ushort xh[64 * 128];

    int t = threadIdx.x;
    int b = blockIdx.x;
    if (b < GEMM_BLOCKS) {
        // ---------------- gemm: h = x_hi * W_hi ----------------
        int r0 = b * 64;
#pragma unroll
        for (int p = 0; p < 8; ++p) {
            int row  = p * 8 + (t >> 5);
            int g    = t & 31;
            int grow = r0 + row;
            float4 v = make_float4(0.f, 0.f, 0.f, 0.f);
            if (grow < N_NODES) v = ((const float4*)(x + (size_t)grow * D))[g];
            ushort4 hi;
            hi.x = f2bf(v.x); hi.y = f2bf(v.y); hi.z = f2bf(v.z); hi.w = f2bf(v.w);
            int bo = (row * 256 + g * 8) ^ ((row & 7) << 4);
            *(ushort4*)((char*)xh + bo) = hi;
        }
        __syncthreads();

        int w  = t >> 6;
        int l  = t & 63;
        int m  = l & 15;
        int gq = l >> 4;

        f32x4 acc[8];
#pragma unroll
        for (int ct = 0; ct < 8; ++ct) acc[ct] = (f32x4){0.f, 0.f, 0.f, 0.f};

#pragma unroll
        for (int ks = 0; ks < 4; ++ks) {
            int row = w * 16 + m;
            int bo  = (row * 256 + gq * 16 + ks * 64) ^ ((row & 7) << 4);
            short8 ah = *(const short8*)((const char*)xh + bo);
#pragma unroll
            for (int ct = 0; ct < 8; ++ct) {
                size_t fb = (((size_t)ct * 4 + ks) * 64 + l) * 8;
                short8 bh = *(const short8*)(wfh + fb);
                acc[ct] = __builtin_amdgcn_mfma_f32_16x16x32_bf16(ah, bh, acc[ct], 0, 0, 0);
            }
        }

        int orow0 = r0 + w * 16 + gq * 4;
#pragma unroll
        for (int ct = 0; ct < 8; ++ct) {
#pragma unroll
            for (int r = 0; r < 4; ++r) {
                int row = orow0 + r;
                if (row < N_NODES) hbf[(size_t)row * D + ct * 16 + m] = f2bf(acc[ct][r]);
            }
        }
    } else {
        // ---------------- fill: dst-sorted packed u32 edges ----------------
        int fb = b - GEMM_BLOCKS;
        int e = fb * 256 + t;
        if (e >= N_EDGES) return;
        int s = src[e];
        int d = dst[e];
        int r = fb & (REP - 1);               // matches deg_cnt replica map
        int pos = atomicAdd(&cursor[(size_t)d * REP + r], 1);
        float w = ew[e] * dinv[s] * dinv[d];
        edge_s[pos] = ((unsigned)f2bf(w) << 16) | (unsigned)s;
    }
}

// ---------------------------------------------------------------------------
// Gather: one wave per node, 8-WAY SPLIT: 8 lanes cover the 128-feature row
// (32 B/lane via two dwordx4), groups q=0..7 process interleaved edge eighths.
// Serial chain per group: ceil(deg/8) ~= 2 links (was 3 at 4-way). Combine
// via shfl_xor(8,16,32).
// ---------------------------------------------------------------------------
__global__ __launch_bounds__(256) void gather_kernel(
        const int* __restrict__ off, const unsigned* __restrict__ edge_s,
        const float* __restrict__ dinv,
        const ushort* __restrict__ hbf, const float* __restrict__ bias,
        float* __restrict__ out) {
    int node = blockIdx.x * 4 + (threadIdx.x >> 6);
    if (node >= N_NODES) return;
    int lane = threadIdx.x & 63;
    int q   = lane >> 3;       // edge group 0..7
    int fl8 = lane & 7;        // feature block: 16*fl8 .. 16*fl8+15

    int begin = off[node];
    int end   = off[node + 1];
    float dd  = dinv[node];
    float sw  = dd * dd;

    float acc[16];
#pragma unroll
    for (int j = 0; j < 16; ++j) acc[j] = 0.f;

    // self-loop contribution on group 0 only
    {
        const short8* hp = (const short8*)(hbf + (size_t)node * D);
        short8 sv0 = hp[fl8 * 2];
        short8 sv1 = hp[fl8 * 2 + 1];
        if (q == 0) {
#pragma unroll
            for (int j = 0; j < 8; ++j) {
                acc[j]     = bf2f((ushort)sv0[j]) * sw;
                acc[8 + j] = bf2f((ushort)sv1[j]) * sw;
            }
        }
    }

    for (int j0 = begin; j0 < end; j0 += 64) {
        int nc = end - j0;
        if (nc > 64) nc = 64;
        unsigned p = 0;
        if (lane < nc) p = edge_s[j0 + lane];
        int iters = (nc + 7) >> 3;
#pragma unroll 2
        for (int k = 0; k < iters; ++k) {
            int ei = k * 8 + q;                        // <= 63 always
            unsigned pe = (unsigned)__shfl((int)p, ei);
            bool valid = ei < nc;
            int   ss = valid ? (int)(pe & 0xFFFFu) : 0;
            float ww = valid ? bf2f((ushort)(pe >> 16)) : 0.0f;
            const short8* hp = (const short8*)(hbf + (size_t)ss * D);
            short8 v0 = hp[fl8 * 2];
            short8 v1 = hp[fl8 * 2 + 1];
#pragma unroll
            for (int j = 0; j < 8; ++j) {
                acc[j]     = fmaf(bf2f((ushort)v0[j]), ww, acc[j]);
                acc[8 + j] = fmaf(bf2f((ushort)v1[j]), ww, acc[8 + j]);
            }
        }
    }

    // combine the 8 groups
#pragma unroll
    for (int j = 0; j < 16; ++j) {
        acc[j] += __shfl_xor(acc[j], 8);
        acc[j] += __shfl_xor(acc[j], 16);
        acc[j] += __shfl_xor(acc[j], 32);
    }

    if (q == 0) {
        // lanes 0..7 write 64 B each: features 16*fl8 .. 16*fl8+15
        float* op = out + (size_t)node * D + fl8 * 16;
        const float4* bp = (const float4*)(bias) + fl8 * 4;
#pragma unroll
        for (int jj = 0; jj < 4; ++jj) {
            float4 bb = bp[jj];
            float4 o4 = make_float4(fmaxf(acc[jj * 4 + 0] + bb.x, 0.f),
                                    fmaxf(acc[jj * 4 + 1] + bb.y, 0.f),
                                    fmaxf(acc[jj * 4 + 2] + bb.z, 0.f),
                                    fmaxf(acc[jj * 4 + 3] + bb.w, 0.f));
            ((float4*)op)[jj] = o4;
        }
    }
}

extern "C" void kernel_launch(void* const* d_in, const int* in_sizes, int n_in,
                              void* d_out, int out_size, void* d_ws, size_t ws_size,
                              hipStream_t stream) {
    const float* x  = (const float*)d_in[0];
    const int*   ei = (const int*)d_in[1];   // [2, E]: src row then dst row
    const float* ew = (const float*)d_in[2];
    const float* W  = (const float*)d_in[3];
    const float* bias = (const float*)d_in[4];
    float*       out = (float*)d_out;

    const int* src = ei;
    const int* dst = ei + N_EDGES;

    // ---- workspace layout (8B-aligned throughout) ----
    ushort*   hbf    = (ushort*)d_ws;                           // N*D bf16  (12.8 MB)
    u64*      degp   = (u64*)(hbf + (size_t)N_NODES * D);       // N*REP u64, [i*REP+r]
    u64*      flags  = degp + (size_t)REP * N_NODES;            // 256 u64
    float*    dinv   = (float*)(flags + 256);                   // N
    int*      off    = (int*)(dinv + N_NODES);                  // N+2
    int*      cursor = off + (N_NODES + 2);                     // N*REP, [i*REP+r]
    unsigned* edge_s = (unsigned*)(cursor + (size_t)REP * N_NODES); // E u32 (2.4 MB)
    ushort*   wfh    = (ushort*)(edge_s + N_EDGES);             // 16384
    size_t need = ((size_t)(wfh + 16384) - (size_t)d_ws);
    if (ws_size < need) return;   // harness ws is ample; never hit

    int n2 = (int)(((size_t)REP * N_NODES * 8 + 256 * 8) / 16);
    prep_kernel<<<ZERO_BLOCKS + 8, 256, 0, stream>>>((ulonglong2*)degp, n2, W, wfh);
    deg_cnt_kernel<<<FILL_BLOCKS, 256, 0, stream>>>(dst, ew, degp);
    scan_fused_kernel<<<NB, SCAN_B, 0, stream>>>(degp, dinv, off, cursor, flags);
    fused_fg_kernel<<<GEMM_BLOCKS + FILL_BLOCKS, 256, 0, stream>>>(
        x, wfh, hbf, src, dst, ew, dinv, cursor, edge_s);
    gather_kernel<<<GATHER_GROUPS, 256, 0, stream>>>(off, edge_s, dinv,
                                                     hbf, bias, out);
}

// Round 21
// 109.234 us; speedup vs baseline: 1.0288x; 1.0288x over previous
//
#include <hip/hip_runtime.h>

#define N_NODES 50000
#define N_EDGES 600000
#define D 128
#define SCAN_B 256
#define NB ((N_NODES + SCAN_B - 1) / SCAN_B)   // 196
#define REP 2
#define FXSHIFT 44
#define GEMM_BLOCKS ((N_NODES + 63) / 64)       // 782
#define FILL_BLOCKS ((N_EDGES + 255) / 256)     // 2344
#define GATHER_GROUPS ((N_NODES + 3) / 4)       // 12500
#define ZERO_BLOCKS 196                          // ceil((REP*N*8+2048)/16/256)

typedef __attribute__((ext_vector_type(8))) short short8;
typedef __attribute__((ext_vector_type(4))) float f32x4;
typedef unsigned long long u64;

__device__ __forceinline__ ushort f2bf(float f) {
    unsigned u = __float_as_uint(f);
    unsigned r = (u + 0x7FFFu + ((u >> 16) & 1u)) >> 16;   // RNE
    return (ushort)r;
}
__device__ __forceinline__ float bf2f(ushort h) {
    return __uint_as_float(((unsigned)h) << 16);
}

// ---------------------------------------------------------------------------
// W fragment computation (bf16 hi only), MFMA B-operand lane order.
// ---------------------------------------------------------------------------
__device__ __forceinline__ void wfrag_body(int t, const float* __restrict__ W,
                                           ushort* __restrict__ wfh) {
    int lane = t & 63;
    int ks   = (t >> 6) & 3;
    int ct   = t >> 8;
    int n  = ct * 16 + (lane & 15);
    int k0 = ks * 32 + (lane >> 4) * 8;
    ushort hv[8];
#pragma unroll
    for (int j = 0; j < 8; ++j) hv[j] = f2bf(W[(k0 + j) * D + n]);
    size_t base = (((size_t)ct * 4 + ks) * 64 + lane) * 8;
#pragma unroll
    for (int j = 0; j < 8; ++j) wfh[base + j] = hv[j];
}

// ---------------------------------------------------------------------------
// Prep (fat): blocks [0,ZERO_BLOCKS) zero degp+flags; the last 8 do wfrag.
// ---------------------------------------------------------------------------
__global__ void prep_kernel(ulonglong2* __restrict__ zp, int n2,
                            const float* __restrict__ W,
                            ushort* __restrict__ wfh) {
    if (blockIdx.x < ZERO_BLOCKS) {
        int i = blockIdx.x * 256 + threadIdx.x;
        if (i < n2) zp[i] = make_ulonglong2(0ull, 0ull);
    } else {
        wfrag_body((blockIdx.x - ZERO_BLOCKS) * 256 + threadIdx.x, W, wfh);
    }
}

// ---------------------------------------------------------------------------
// Per-edge: one packed u64 atomic. degp INTERLEAVED [node*REP + r].
// ---------------------------------------------------------------------------
__global__ void deg_cnt_kernel(const int* __restrict__ dst,
                               const float* __restrict__ ew,
                               u64* __restrict__ degp) {
    int e = blockIdx.x * 256 + threadIdx.x;
    if (e < N_EDGES) {
        int d = dst[e];
        int r = blockIdx.x & (REP - 1);
        u64 fx = (u64)llrintf(ew[e] * 16777216.0f);
        atomicAdd(&degp[(size_t)d * REP + r], (1ull << FXSHIFT) | fx);
    }
}

// ---------------------------------------------------------------------------
// Single-pass fused scan, wave-parallel aggregate rake (R13-proven).
// ---------------------------------------------------------------------------
__global__ void scan_fused_kernel(const u64* __restrict__ degp,
                                  float* __restrict__ dinv,
                                  int* __restrict__ off,
                                  int* __restrict__ cursor,
                                  u64* __restrict__ flags) {
    __shared__ int s[SCAN_B];
    __shared__ int sbase_sh;
    int t = threadIdx.x;
    int i = blockIdx.x * SCAN_B + t;
    int v = 0;
    u64 pr[REP];
    if (i < N_NODES) {
        u64 fxsum = 0;
        int c = 0;
        const u64* dp = degp + (size_t)i * REP;
#pragma unroll
        for (int r = 0; r < REP; ++r) {
            pr[r] = dp[r];
            fxsum += pr[r] & ((1ull << FXSHIFT) - 1);
            c += (int)(pr[r] >> FXSHIFT);
        }
        dinv[i] = rsqrtf(1.0f + (float)fxsum * (1.0f / 16777216.0f));
        v = c;
    }
    s[t] = v;
    __syncthreads();
    for (int o = 1; o < SCAN_B; o <<= 1) {
        int x = (t >= o) ? s[t - o] : 0;
        __syncthreads();
        s[t] += x;
        __syncthreads();
    }
    int localExcl = s[t] - v;
    int blockSum  = s[SCAN_B - 1];

    if (t == 0) {
        __hip_atomic_store(&flags[blockIdx.x], (1ull << 62) | (u64)blockSum,
                           __ATOMIC_RELEASE, __HIP_MEMORY_SCOPE_AGENT);
    }
    if (t < 64) {
        u64 sum = 0;
        for (int j0 = 0; j0 < (int)blockIdx.x; j0 += 64) {
            int j = j0 + t;
            u64 f = 0;
            if (j < (int)blockIdx.x) {
                do {
                    f = __hip_atomic_load(&flags[j], __ATOMIC_ACQUIRE,
                                          __HIP_MEMORY_SCOPE_AGENT);
                } while (f == 0ull);
            }
            sum += f & ((1ull << 62) - 1);
        }
#pragma unroll
        for (int o = 32; o > 0; o >>= 1)
            sum += (u64)__shfl_xor((long long)sum, o);
        if (t == 0) sbase_sh = (int)sum;
    }
    __syncthreads();

    if (i < N_NODES) {
        int o = localExcl + sbase_sh;
        off[i] = o;
        int run = o;
        int* cp = cursor + (size_t)i * REP;
#pragma unroll
        for (int r = 0; r < REP; ++r) {
            cp[r] = run;
            run += (int)(pr[r] >> FXSHIFT);
        }
    }
    if (i == 0) off[N_NODES] = N_EDGES;
}

// ---------------------------------------------------------------------------
// Fat compute kernel (R16-proven structure): blocks [0,GEMM_BLOCKS) = gemm
// 64-row tiles (h = x_hi * W_hi, row-split waves); rest = fill.
// Fill writes PACKED u32 edges: (norm_bf16 << 16) | src_u16 (src < 65536).
// ---------------------------------------------------------------------------
__global__ __launch_bounds__(256) void fused_fg_kernel(
        const float* __restrict__ x,
        const ushort* __restrict__ wfh,
        ushort* __restrict__ hbf,
        const int* __restrict__ src, const int* __restrict__ dst,
        const float* __restrict__ ew, const float* __restrict__ dinv,
        int* __restrict__ cursor, unsigned* __restrict__ edge_s) {
    __shared__ __attribute__((aligned(16))) ushort xh[64 * 128];

    int t = threadIdx.x;
    int b = blockIdx.x;
    if (b < GEMM_BLOCKS) {
        // ---------------- gemm: h = x_hi * W_hi ----------------
        int r0 = b * 64;
#pragma unroll
        for (int p = 0; p < 8; ++p) {
            int row  = p * 8 + (t >> 5);
            int g    = t & 31;
            int grow = r0 + row;
            float4 v = make_float4(0.f, 0.f, 0.f, 0.f);
            if (grow < N_NODES) v = ((const float4*)(x + (size_t)grow * D))[g];
            ushort4 hi;
            hi.x = f2bf(v.x); hi.y = f2bf(v.y); hi.z = f2bf(v.z); hi.w = f2bf(v.w);
            int bo = (row * 256 + g * 8) ^ ((row & 7) << 4);
            *(ushort4*)((char*)xh + bo) = hi;
        }
        __syncthreads();

        int w  = t >> 6;
        int l  = t & 63;
        int m  = l & 15;
        int gq = l >> 4;

        f32x4 acc[8];
#pragma unroll
        for (int ct = 0; ct < 8; ++ct) acc[ct] = (f32x4){0.f, 0.f, 0.f, 0.f};

#pragma unroll
        for (int ks = 0; ks < 4; ++ks) {
            int row = w * 16 + m;
            int bo  = (row * 256 + gq * 16 + ks * 64) ^ ((row & 7) << 4);
            short8 ah = *(const short8*)((const char*)xh + bo);
#pragma unroll
            for (int ct = 0; ct < 8; ++ct) {
                size_t fb = (((size_t)ct * 4 + ks) * 64 + l) * 8;
                short8 bh = *(const short8*)(wfh + fb);
                acc[ct] = __builtin_amdgcn_mfma_f32_16x16x32_bf16(ah, bh, acc[ct], 0, 0, 0);
            }
        }

        int orow0 = r0 + w * 16 + gq * 4;
#pragma unroll
        for (int ct = 0; ct < 8; ++ct) {
#pragma unroll
            for (int r = 0; r < 4; ++r) {
                int row = orow0 + r;
                if (row < N_NODES) hbf[(size_t)row * D + ct * 16 + m] = f2bf(acc[ct][r]);
            }
        }
    } else {
        // ---------------- fill: dst-sorted packed u32 edges ----------------
        int fb = b - GEMM_BLOCKS;
        int e = fb * 256 + t;
        if (e >= N_EDGES) return;
        int s = src[e];
        int d = dst[e];
        int r = fb & (REP - 1);               // matches deg_cnt replica map
        int pos = atomicAdd(&cursor[(size_t)d * REP + r], 1);
        float w = ew[e] * dinv[s] * dinv[d];
        edge_s[pos] = ((unsigned)f2bf(w) << 16) | (unsigned)s;
    }
}

// ---------------------------------------------------------------------------
// Gather (R19-proven 4-way split): one wave per node, 16 lanes cover the
// 128-feature row (short8 = 16 B/lane), groups q=0..3 process interleaved
// edge quarters. u32 edge meta, 32-bit shfl.
// ---------------------------------------------------------------------------
__global__ __launch_bounds__(256) void gather_kernel(
        const int* __restrict__ off, const unsigned* __restrict__ edge_s,
        const float* __restrict__ dinv,
        const ushort* __restrict__ hbf, const float* __restrict__ bias,
        float* __restrict__ out) {
    int node = blockIdx.x * 4 + (threadIdx.x >> 6);
    if (node >= N_NODES) return;
    int lane = threadIdx.x & 63;
    int q  = lane >> 4;
    int fl = lane & 15;

    int begin = off[node];
    int end   = off[node + 1];
    float dd  = dinv[node];
    float sw  = dd * dd;

    float acc[8] = {0.f, 0.f, 0.f, 0.f, 0.f, 0.f, 0.f, 0.f};

    short8 sv = ((const short8*)(hbf + (size_t)node * D))[fl];
    if (q == 0) {
#pragma unroll
        for (int j = 0; j < 8; ++j) acc[j] = bf2f((ushort)sv[j]) * sw;
    }

    for (int j0 = begin; j0 < end; j0 += 64) {
        int nc = end - j0;
        if (nc > 64) nc = 64;
        unsigned p = 0;
        if (lane < nc) p = edge_s[j0 + lane];
        int iters = (nc + 3) >> 2;
#pragma unroll 2
        for (int k = 0; k < iters; ++k) {
            int ei = k * 4 + q;
            unsigned pe = (unsigned)__shfl((int)p, ei);
            bool valid = ei < nc;
            int   ss = valid ? (int)(pe & 0xFFFFu) : 0;
            float ww = valid ? bf2f((ushort)(pe >> 16)) : 0.0f;
            short8 v = ((const short8*)(hbf + (size_t)ss * D))[fl];
#pragma unroll
            for (int j = 0; j < 8; ++j)
                acc[j] = fmaf(bf2f((ushort)v[j]), ww, acc[j]);
        }
    }

#pragma unroll
    for (int j = 0; j < 8; ++j) {
        acc[j] += __shfl_xor(acc[j], 16);
        acc[j] += __shfl_xor(acc[j], 32);
    }

    if (q == 0) {
        float4 b1 = ((const float4*)bias)[fl * 2];
        float4 b2 = ((const float4*)bias)[fl * 2 + 1];
        float4 o1 = make_float4(fmaxf(acc[0] + b1.x, 0.f), fmaxf(acc[1] + b1.y, 0.f),
                                fmaxf(acc[2] + b1.z, 0.f), fmaxf(acc[3] + b1.w, 0.f));
        float4 o2 = make_float4(fmaxf(acc[4] + b2.x, 0.f), fmaxf(acc[5] + b2.y, 0.f),
                                fmaxf(acc[6] + b2.z, 0.f), fmaxf(acc[7] + b2.w, 0.f));
        ((float4*)(out + (size_t)node * D))[fl * 2]     = o1;
        ((float4*)(out + (size_t)node * D))[fl * 2 + 1] = o2;
    }
}

extern "C" void kernel_launch(void* const* d_in, const int* in_sizes, int n_in,
                              void* d_out, int out_size, void* d_ws, size_t ws_size,
                              hipStream_t stream) {
    const float* x  = (const float*)d_in[0];
    const int*   ei = (const int*)d_in[1];   // [2, E]: src row then dst row
    const float* ew = (const float*)d_in[2];
    const float* W  = (const float*)d_in[3];
    const float* bias = (const float*)d_in[4];
    float*       out = (float*)d_out;

    const int* src = ei;
    const int* dst = ei + N_EDGES;

    // ---- workspace layout (8B-aligned throughout) ----
    ushort*   hbf    = (ushort*)d_ws;                           // N*D bf16  (12.8 MB)
    u64*      degp   = (u64*)(hbf + (size_t)N_NODES * D);       // N*REP u64, [i*REP+r]
    u64*      flags  = degp + (size_t)REP * N_NODES;            // 256 u64
    float*    dinv   = (float*)(flags + 256);                   // N
    int*      off    = (int*)(dinv + N_NODES);                  // N+2
    int*      cursor = off + (N_NODES + 2);                     // N*REP, [i*REP+r]
    unsigned* edge_s = (unsigned*)(cursor + (size_t)REP * N_NODES); // E u32 (2.4 MB)
    ushort*   wfh    = (ushort*)(edge_s + N_EDGES);             // 16384
    size_t need = ((size_t)(wfh + 16384) - (size_t)d_ws);
    if (ws_size < need) return;   // harness ws is ample; never hit

    int n2 = (int)(((size_t)REP * N_NODES * 8 + 256 * 8) / 16);
    prep_kernel<<<ZERO_BLOCKS + 8, 256, 0, stream>>>((ulonglong2*)degp, n2, W, wfh);
    deg_cnt_kernel<<<FILL_BLOCKS, 256, 0, stream>>>(dst, ew, degp);
    scan_fused_kernel<<<NB, SCAN_B, 0, stream>>>(degp, dinv, off, cursor, flags);
    fused_fg_kernel<<<GEMM_BLOCKS + FILL_BLOCKS, 256, 0, stream>>>(
        x, wfh, hbf, src, dst, ew, dinv, cursor, edge_s);
    gather_kernel<<<GATHER_GROUPS, 256, 0, stream>>>(off, edge_s, dinv,
                                                     hbf, bias, out);
}

// Round 22
// 108.139 us; speedup vs baseline: 1.0393x; 1.0101x over previous
//
#include <hip/hip_runtime.h>

#define N_NODES 50000
#define N_EDGES 600000
#define D 128
#define SCAN_B 256
#define NB ((N_NODES + SCAN_B - 1) / SCAN_B)   // 196
#define REP 4
#define FXSHIFT 44
#define GEMM_BLOCKS ((N_NODES + 63) / 64)       // 782
#define FILL_BLOCKS ((N_EDGES + 255) / 256)     // 2344
#define GATHER_GROUPS ((N_NODES + 3) / 4)       // 12500
#define ZERO_BLOCKS 392

typedef __attribute__((ext_vector_type(8))) short short8;
typedef __attribute__((ext_vector_type(4))) float f32x4;
typedef unsigned long long u64;

__device__ __forceinline__ ushort f2bf(float f) {
    unsigned u = __float_as_uint(f);
    unsigned r = (u + 0x7FFFu + ((u >> 16) & 1u)) >> 16;   // RNE
    return (ushort)r;
}
__device__ __forceinline__ float bf2f(ushort h) {
    return __uint_as_float(((unsigned)h) << 16);
}

// ---------------------------------------------------------------------------
// W fragment computation (bf16 hi only), MFMA B-operand lane order.
// ---------------------------------------------------------------------------
__device__ __forceinline__ void wfrag_body(int t, const float* __restrict__ W,
                                           ushort* __restrict__ wfh) {
    int lane = t & 63;
    int ks   = (t >> 6) & 3;
    int ct   = t >> 8;
    int n  = ct * 16 + (lane & 15);
    int k0 = ks * 32 + (lane >> 4) * 8;
    ushort hv[8];
#pragma unroll
    for (int j = 0; j < 8; ++j) hv[j] = f2bf(W[(k0 + j) * D + n]);
    size_t base = (((size_t)ct * 4 + ks) * 64 + lane) * 8;
#pragma unroll
    for (int j = 0; j < 8; ++j) wfh[base + j] = hv[j];
}

// ---------------------------------------------------------------------------
// Prep (fat): blocks [0,ZERO_BLOCKS) zero degp+flags; the last 8 do wfrag.
// ---------------------------------------------------------------------------
__global__ void prep_kernel(ulonglong2* __restrict__ zp, int n2,
                            const float* __restrict__ W,
                            ushort* __restrict__ wfh) {
    if (blockIdx.x < ZERO_BLOCKS) {
        int i = blockIdx.x * 256 + threadIdx.x;
        if (i < n2) zp[i] = make_ulonglong2(0ull, 0ull);
    } else {
        wfrag_body((blockIdx.x - ZERO_BLOCKS) * 256 + threadIdx.x, W, wfh);
    }
}

// ---------------------------------------------------------------------------
// Per-edge: one packed u64 atomic. degp INTERLEAVED [node*REP + r].
// ---------------------------------------------------------------------------
__global__ void deg_cnt_kernel(const int* __restrict__ dst,
                               const float* __restrict__ ew,
                               u64* __restrict__ degp) {
    int e = blockIdx.x * 256 + threadIdx.x;
    if (e < N_EDGES) {
        int d = dst[e];
        int r = blockIdx.x & (REP - 1);
        u64 fx = (u64)llrintf(ew[e] * 16777216.0f);
        atomicAdd(&degp[(size_t)d * REP + r], (1ull << FXSHIFT) | fx);
    }
}

// ---------------------------------------------------------------------------
// Single-pass fused scan, wave-parallel aggregate rake (R13-proven).
// ---------------------------------------------------------------------------
__global__ void scan_fused_kernel(const u64* __restrict__ degp,
                                  float* __restrict__ dinv,
                                  int* __restrict__ off,
                                  int* __restrict__ cursor,
                                  u64* __restrict__ flags) {
    __shared__ int s[SCAN_B];
    __shared__ int sbase_sh;
    int t = threadIdx.x;
    int i = blockIdx.x * SCAN_B + t;
    int v = 0;
    u64 pr[REP];
    if (i < N_NODES) {
        u64 fxsum = 0;
        int c = 0;
        const u64* dp = degp + (size_t)i * REP;
#pragma unroll
        for (int r = 0; r < REP; ++r) {
            pr[r] = dp[r];
            fxsum += pr[r] & ((1ull << FXSHIFT) - 1);
            c += (int)(pr[r] >> FXSHIFT);
        }
        dinv[i] = rsqrtf(1.0f + (float)fxsum * (1.0f / 16777216.0f));
        v = c;
    }
    s[t] = v;
    __syncthreads();
    for (int o = 1; o < SCAN_B; o <<= 1) {
        int x = (t >= o) ? s[t - o] : 0;
        __syncthreads();
        s[t] += x;
        __syncthreads();
    }
    int localExcl = s[t] - v;
    int blockSum  = s[SCAN_B - 1];

    if (t == 0) {
        __hip_atomic_store(&flags[blockIdx.x], (1ull << 62) | (u64)blockSum,
                           __ATOMIC_RELEASE, __HIP_MEMORY_SCOPE_AGENT);
    }
    if (t < 64) {
        u64 sum = 0;
        for (int j0 = 0; j0 < (int)blockIdx.x; j0 += 64) {
            int j = j0 + t;
            u64 f = 0;
            if (j < (int)blockIdx.x) {
                do {
                    f = __hip_atomic_load(&flags[j], __ATOMIC_ACQUIRE,
                                          __HIP_MEMORY_SCOPE_AGENT);
                } while (f == 0ull);
            }
            sum += f & ((1ull << 62) - 1);
        }
#pragma unroll
        for (int o = 32; o > 0; o >>= 1)
            sum += (u64)__shfl_xor((long long)sum, o);
        if (t == 0) sbase_sh = (int)sum;
    }
    __syncthreads();

    if (i < N_NODES) {
        int o = localExcl + sbase_sh;
        off[i] = o;
        int run = o;
        int* cp = cursor + (size_t)i * REP;
#pragma unroll
        for (int r = 0; r < REP; ++r) {
            cp[r] = run;
            run += (int)(pr[r] >> FXSHIFT);
        }
    }
    if (i == 0) off[N_NODES] = N_EDGES;
}

// ---------------------------------------------------------------------------
// Fat compute kernel (R16-proven structure): blocks [0,GEMM_BLOCKS) = gemm
// 64-row tiles (h = x_hi * W_hi, row-split waves); rest = fill.
// Fill writes PACKED u32 edges: (norm_bf16 << 16) | src_u16 (src < 65536).
// ---------------------------------------------------------------------------
__global__ __launch_bounds__(256) void fused_fg_kernel(
        const float* __restrict__ x,
        const ushort* __restrict__ wfh,
        ushort* __restrict__ hbf,
        const int* __restrict__ src, const int* __restrict__ dst,
        const float* __restrict__ ew, const float* __restrict__ dinv,
        int* __restrict__ cursor, unsigned* __restrict__ edge_s) {
    __shared__ __attribute__((aligned(16))) ushort xh[64 * 128];

    int t = threadIdx.x;
    int b = blockIdx.x;
    if (b < GEMM_BLOCKS) {
        // ---------------- gemm: h = x_hi * W_hi ----------------
        int r0 = b * 64;
#pragma unroll
        for (int p = 0; p < 8; ++p) {
            int row  = p * 8 + (t >> 5);
            int g    = t & 31;
            int grow = r0 + row;
            float4 v = make_float4(0.f, 0.f, 0.f, 0.f);
            if (grow < N_NODES) v = ((const float4*)(x + (size_t)grow * D))[g];
            ushort4 hi;
            hi.x = f2bf(v.x); hi.y = f2bf(v.y); hi.z = f2bf(v.z); hi.w = f2bf(v.w);
            int bo = (row * 256 + g * 8) ^ ((row & 7) << 4);
            *(ushort4*)((char*)xh + bo) = hi;
        }
        __syncthreads();

        int w  = t >> 6;
        int l  = t & 63;
        int m  = l & 15;
        int gq = l >> 4;

        f32x4 acc[8];
#pragma unroll
        for (int ct = 0; ct < 8; ++ct) acc[ct] = (f32x4){0.f, 0.f, 0.f, 0.f};

#pragma unroll
        for (int ks = 0; ks < 4; ++ks) {
            int row = w * 16 + m;
            int bo  = (row * 256 + gq * 16 + ks * 64) ^ ((row & 7) << 4);
            short8 ah = *(const short8*)((const char*)xh + bo);
#pragma unroll
            for (int ct = 0; ct < 8; ++ct) {
                size_t fb = (((size_t)ct * 4 + ks) * 64 + l) * 8;
                short8 bh = *(const short8*)(wfh + fb);
                acc[ct] = __builtin_amdgcn_mfma_f32_16x16x32_bf16(ah, bh, acc[ct], 0, 0, 0);
            }
        }

        int orow0 = r0 + w * 16 + gq * 4;
#pragma unroll
        for (int ct = 0; ct < 8; ++ct) {
#pragma unroll
            for (int r = 0; r < 4; ++r) {
                int row = orow0 + r;
                if (row < N_NODES) hbf[(size_t)row * D + ct * 16 + m] = f2bf(acc[ct][r]);
            }
        }
    } else {
        // ---------------- fill: dst-sorted packed u32 edges ----------------
        int fb = b - GEMM_BLOCKS;
        int e = fb * 256 + t;
        if (e >= N_EDGES) return;
        int s = src[e];
        int d = dst[e];
        int r = fb & (REP - 1);               // matches deg_cnt replica map
        int pos = atomicAdd(&cursor[(size_t)d * REP + r], 1);
        float w = ew[e] * dinv[s] * dinv[d];
        edge_s[pos] = ((unsigned)f2bf(w) << 16) | (unsigned)s;
    }
}

// ---------------------------------------------------------------------------
// Gather (R19-proven 4-way split): one wave per node, 16 lanes cover the
// 128-feature row (short8 = 16 B/lane), groups q=0..3 process interleaved
// edge quarters. u32 edge meta, 32-bit shfl.
// ---------------------------------------------------------------------------
__global__ __launch_bounds__(256) void gather_kernel(
        const int* __restrict__ off, const unsigned* __restrict__ edge_s,
        const float* __restrict__ dinv,
        const ushort* __restrict__ hbf, const float* __restrict__ bias,
        float* __restrict__ out) {
    int node = blockIdx.x * 4 + (threadIdx.x >> 6);
    if (node >= N_NODES) return;
    int lane = threadIdx.x & 63;
    int q  = lane >> 4;
    int fl = lane & 15;

    int begin = off[node];
    int end   = off[node + 1];
    float dd  = dinv[node];
    float sw  = dd * dd;

    float acc[8] = {0.f, 0.f, 0.f, 0.f, 0.f, 0.f, 0.f, 0.f};

    short8 sv = ((const short8*)(hbf + (size_t)node * D))[fl];
    if (q == 0) {
#pragma unroll
        for (int j = 0; j < 8; ++j) acc[j] = bf2f((ushort)sv[j]) * sw;
    }

    for (int j0 = begin; j0 < end; j0 += 64) {
        int nc = end - j0;
        if (nc > 64) nc = 64;
        unsigned p = 0;
        if (lane < nc) p = edge_s[j0 + lane];
        int iters = (nc + 3) >> 2;
#pragma unroll 2
        for (int k = 0; k < iters; ++k) {
            int ei = k * 4 + q;
            unsigned pe = (unsigned)__shfl((int)p, ei);
            bool valid = ei < nc;
            int   ss = valid ? (int)(pe & 0xFFFFu) : 0;
            float ww = valid ? bf2f((ushort)(pe >> 16)) : 0.0f;
            short8 v = ((const short8*)(hbf + (size_t)ss * D))[fl];
#pragma unroll
            for (int j = 0; j < 8; ++j)
                acc[j] = fmaf(bf2f((ushort)v[j]), ww, acc[j]);
        }
    }

#pragma unroll
    for (int j = 0; j < 8; ++j) {
        acc[j] += __shfl_xor(acc[j], 16);
        acc[j] += __shfl_xor(acc[j], 32);
    }

    if (q == 0) {
        float4 b1 = ((const float4*)bias)[fl * 2];
        float4 b2 = ((const float4*)bias)[fl * 2 + 1];
        float4 o1 = make_float4(fmaxf(acc[0] + b1.x, 0.f), fmaxf(acc[1] + b1.y, 0.f),
                                fmaxf(acc[2] + b1.z, 0.f), fmaxf(acc[3] + b1.w, 0.f));
        float4 o2 = make_float4(fmaxf(acc[4] + b2.x, 0.f), fmaxf(acc[5] + b2.y, 0.f),
                                fmaxf(acc[6] + b2.z, 0.f), fmaxf(acc[7] + b2.w, 0.f));
        ((float4*)(out + (size_t)node * D))[fl * 2]     = o1;
        ((float4*)(out + (size_t)node * D))[fl * 2 + 1] = o2;
    }
}

extern "C" void kernel_launch(void* const* d_in, const int* in_sizes, int n_in,
                              void* d_out, int out_size, void* d_ws, size_t ws_size,
                              hipStream_t stream) {
    const float* x  = (const float*)d_in[0];
    const int*   ei = (const int*)d_in[1];   // [2, E]: src row then dst row
    const float* ew = (const float*)d_in[2];
    const float* W  = (const float*)d_in[3];
    const float* bias = (const float*)d_in[4];
    float*       out = (float*)d_out;

    const int* src = ei;
    const int* dst = ei + N_EDGES;

    // ---- workspace layout (8B-aligned throughout) ----
    ushort*   hbf    = (ushort*)d_ws;                           // N*D bf16  (12.8 MB)
    u64*      degp   = (u64*)(hbf + (size_t)N_NODES * D);       // N*REP u64, [i*REP+r]
    u64*      flags  = degp + (size_t)REP * N_NODES;            // 256 u64
    float*    dinv   = (float*)(flags + 256);                   // N
    int*      off    = (int*)(dinv + N_NODES);                  // N+2
    int*      cursor = off + (N_NODES + 2);                     // N*REP, [i*REP+r]
    unsigned* edge_s = (unsigned*)(cursor + (size_t)REP * N_NODES); // E u32 (2.4 MB)
    ushort*   wfh    = (ushort*)(edge_s + N_EDGES);             // 16384
    size_t need = ((size_t)(wfh + 16384) - (size_t)d_ws);
    if (ws_size < need) return;   // harness ws is ample; never hit

    int n2 = (int)(((size_t)REP * N_NODES * 8 + 256 * 8) / 16);
    prep_kernel<<<ZERO_BLOCKS + 8, 256, 0, stream>>>((ulonglong2*)degp, n2, W, wfh);
    deg_cnt_kernel<<<FILL_BLOCKS, 256, 0, stream>>>(dst, ew, degp);
    scan_fused_kernel<<<NB, SCAN_B, 0, stream>>>(degp, dinv, off, cursor, flags);
    fused_fg_kernel<<<GEMM_BLOCKS + FILL_BLOCKS, 256, 0, stream>>>(
        x, wfh, hbf, src, dst, ew, dinv, cursor, edge_s);
    gather_kernel<<<GATHER_GROUPS, 256, 0, stream>>>(off, edge_s, dinv,
                                                     hbf, bias, out);
}